// Round 1
// baseline (119.399 us; speedup 1.0000x reference)
//
#include <hip/hip_runtime.h>

// Problem constants (match reference)
#define BB 8
#define NN 4096
#define GRES 64
#define GG (GRES * GRES)          // 4096 grid cells
#define NSEG 16                   // split N into 16 segments for parallelism
#define SEGPTS (NN / NSEG)        // 256 points per segment
#define GPT 4                     // grid cells per thread
#define TPB 256
#define TILE (TPB * GPT)          // 1024 cells per block
#define NTILES (GG / TILE)        // 4 tiles

// -0.5/sigma^2 * log2(e) with sigma=0.1  ->  -50 * 1.4426950408889634
__device__ __constant__ float kC2 = -72.13475204444817f;
#define STEP (2.0f / 63.0f)
#define EPS 1e-5f

__global__ __launch_bounds__(TPB) void rbf_accum(
    const float* __restrict__ x_c,   // (B, N, 2)
    const float* __restrict__ y_c,   // (B, N, 1)
    const float* __restrict__ t_c,   // (B, N, 1)
    const int*  __restrict__ mask,   // (B, N)  (int32; nonzero = drop)
    float* __restrict__ out)         // (B, 3, G) accumulated raw sums
{
    __shared__ float4 sm[SEGPTS];    // {x0, x1, y, t} per point

    const int blk  = blockIdx.x;
    const int tile = blk & (NTILES - 1);
    const int seg  = (blk / NTILES) & (NSEG - 1);
    const int b    = blk / (NTILES * NSEG);
    const int tid  = threadIdx.x;

    // Stage this segment's points into LDS (one point per thread).
    {
        const int n = seg * SEGPTS + tid;
        const float2 xv = ((const float2*)x_c)[b * NN + n];
        const float  yv = y_c[b * NN + n];
        const float  tv = t_c[b * NN + n];
        const int    m  = mask[b * NN + n];
        // Masked point: push x to 1e18 -> d2 ~ 1e36 -> exp2(-7e37) == 0 exactly.
        sm[tid] = make_float4(m ? 1e18f : xv.x, xv.y, yv, tv);
    }
    __syncthreads();

    // This thread's 4 consecutive grid cells (same row i, columns j0..j0+3).
    const int g0 = tile * TILE + tid * GPT;
    const int i  = g0 >> 6;
    const int j0 = g0 & 63;
    const float gy = fmaf((float)i, STEP, -1.0f);
    float gx[GPT];
#pragma unroll
    for (int k = 0; k < GPT; ++k) gx[k] = fmaf((float)(j0 + k), STEP, -1.0f);

    float den[GPT], wy[GPT], wt[GPT];
#pragma unroll
    for (int k = 0; k < GPT; ++k) { den[k] = 0.f; wy[k] = 0.f; wt[k] = 0.f; }

    const float c2 = kC2;
#pragma unroll 2
    for (int p = 0; p < SEGPTS; ++p) {
        const float4 pt = sm[p];            // broadcast read, conflict-free
        const float dy  = pt.y - gy;
        const float dy2 = dy * dy;
#pragma unroll
        for (int k = 0; k < GPT; ++k) {
            const float dx = pt.x - gx[k];
            const float d2 = fmaf(dx, dx, dy2);
            const float w  = exp2f(d2 * c2);   // native v_exp_f32
            den[k] += w;
            wy[k] = fmaf(w, pt.z, wy[k]);
            wt[k] = fmaf(w, pt.w, wt[k]);
        }
    }

    float* ob = out + (size_t)b * 3 * GG;
#pragma unroll
    for (int k = 0; k < GPT; ++k) {
        atomicAdd(ob + g0 + k,          den[k]);
        atomicAdd(ob + GG + g0 + k,     wy[k]);
        atomicAdd(ob + 2 * GG + g0 + k, wt[k]);
    }
}

__global__ __launch_bounds__(256) void rbf_final(float* __restrict__ out)
{
    const int idx = blockIdx.x * 256 + threadIdx.x;   // over B*G
    const int b = idx >> 12;
    const int g = idx & (GG - 1);
    float* ob = out + (size_t)b * 3 * GG;
    const float den = ob[g];
    const float inv = 1.0f / (den + EPS);
    ob[GG + g]     *= inv;
    ob[2 * GG + g] *= inv;
}

extern "C" void kernel_launch(void* const* d_in, const int* in_sizes, int n_in,
                              void* d_out, int out_size, void* d_ws, size_t ws_size,
                              hipStream_t stream) {
    const float* x_c  = (const float*)d_in[0];
    const float* y_c  = (const float*)d_in[1];
    const float* t_c  = (const float*)d_in[2];
    const int*   mask = (const int*)d_in[3];
    float* out = (float*)d_out;

    // d_out is poisoned 0xAA before every timed launch; zero it (we atomically
    // accumulate raw sums directly into it).
    hipMemsetAsync(out, 0, (size_t)BB * 3 * GG * sizeof(float), stream);

    rbf_accum<<<BB * NSEG * NTILES, TPB, 0, stream>>>(x_c, y_c, t_c, mask, out);
    rbf_final<<<(BB * GG) / 256, 256, 0, stream>>>(out);
}

// Round 2
// 89.207 us; speedup vs baseline: 1.3385x; 1.3385x over previous
//
#include <hip/hip_runtime.h>

// Problem constants (match reference)
#define BB 8
#define NN 4096
#define GRES 64
#define GG (GRES * GRES)          // 4096 grid cells
#define NCHUNK 64                 // K-chunks per batch
#define CPTS (NN / NCHUNK)        // 64 points per chunk
#define TPB 256

// -0.5/sigma^2 * log2(e) with sigma=0.1  ->  -50 * 1.4426950408889634
#define C2 (-72.13475204444817f)
#define STEP (2.0f / 63.0f)
#define EPS 1e-5f

__device__ __forceinline__ float gcoord(int j) {
    return fmaf((float)j, STEP, -1.0f);
}

// Stage 1: separable weights + rank-CPTS update of a 192x64 tile.
// Each block: one (batch, K-chunk). Output: partial tile in ws (PARTIAL=1)
// or atomicAdd into out (PARTIAL=0).
template <int PARTIAL>
__global__ __launch_bounds__(TPB) void rbf_stage1(
    const float* __restrict__ x_c,   // (B, N, 2)
    const float* __restrict__ y_c,   // (B, N)
    const float* __restrict__ t_c,   // (B, N)
    const int*  __restrict__ mask,   // (B, N) int32, nonzero = drop
    float* __restrict__ dst)         // PARTIAL: ws (B,NCHUNK,3,G); else out (B,3,G)
{
    __shared__ __align__(16) float wx[CPTS][64];    // 16 KB: exp(c*dx^2)
    __shared__ __align__(16) float A[CPTS][192];    // 48 KB: [wy, wy*y, wy*t]

    const int blk   = blockIdx.x;
    const int chunk = blk & (NCHUNK - 1);
    const int b     = blk >> 6;
    const int tid   = threadIdx.x;

    // ---- Phase A: fill wx and A for this chunk's 64 points ----
    {
        const int p = tid >> 2;          // point within chunk (0..63)
        const int q = tid & 3;           // quarter (16 columns each)
        const int n = chunk * CPTS + p;
        const float2 xv = ((const float2*)x_c)[b * NN + n];
        const float  yv = y_c[b * NN + n];
        const float  tv = t_c[b * NN + n];
        const float  mfac = mask[b * NN + n] ? 0.0f : 1.0f;

        const float px = xv.x, py = xv.y;
#pragma unroll
        for (int m = 0; m < 4; ++m) {
            const int j = q * 16 + m * 4;
            float4 w;
            { float d = px - gcoord(j + 0); w.x = exp2f(C2 * d * d); }
            { float d = px - gcoord(j + 1); w.y = exp2f(C2 * d * d); }
            { float d = px - gcoord(j + 2); w.z = exp2f(C2 * d * d); }
            { float d = px - gcoord(j + 3); w.w = exp2f(C2 * d * d); }
            *(float4*)&wx[p][j] = w;

            const int i = j;  // same 16-range for rows
            float4 e;
            { float d = py - gcoord(i + 0); e.x = mfac * exp2f(C2 * d * d); }
            { float d = py - gcoord(i + 1); e.y = mfac * exp2f(C2 * d * d); }
            { float d = py - gcoord(i + 2); e.z = mfac * exp2f(C2 * d * d); }
            { float d = py - gcoord(i + 3); e.w = mfac * exp2f(C2 * d * d); }
            *(float4*)&A[p][i] = e;
            float4 ay = make_float4(e.x * yv, e.y * yv, e.z * yv, e.w * yv);
            *(float4*)&A[p][64 + i] = ay;
            float4 at = make_float4(e.x * tv, e.y * tv, e.z * tv, e.w * tv);
            *(float4*)&A[p][128 + i] = at;
        }
    }
    __syncthreads();

    // ---- Phase B: rank-CPTS update. Thread owns 3ch x 4i x 4j outputs ----
    const int j0 = (tid & 15) * 4;
    const int i0 = (tid >> 4) * 4;

    float acc[3][4][4];
#pragma unroll
    for (int c = 0; c < 3; ++c)
#pragma unroll
        for (int ii = 0; ii < 4; ++ii)
#pragma unroll
            for (int jj = 0; jj < 4; ++jj) acc[c][ii][jj] = 0.0f;

#pragma unroll 2
    for (int p = 0; p < CPTS; ++p) {
        const float4 wxv = *(const float4*)&wx[p][j0];
        const float4 a0v = *(const float4*)&A[p][i0];
        const float4 a1v = *(const float4*)&A[p][64 + i0];
        const float4 a2v = *(const float4*)&A[p][128 + i0];
        const float wxa[4] = {wxv.x, wxv.y, wxv.z, wxv.w};
        const float aa[3][4] = {{a0v.x, a0v.y, a0v.z, a0v.w},
                                {a1v.x, a1v.y, a1v.z, a1v.w},
                                {a2v.x, a2v.y, a2v.z, a2v.w}};
#pragma unroll
        for (int c = 0; c < 3; ++c)
#pragma unroll
            for (int ii = 0; ii < 4; ++ii)
#pragma unroll
                for (int jj = 0; jj < 4; ++jj)
                    acc[c][ii][jj] = fmaf(aa[c][ii], wxa[jj], acc[c][ii][jj]);
    }

    // ---- Epilogue ----
    if (PARTIAL) {
        float* tb = dst + ((size_t)(b * NCHUNK + chunk) * 3) * GG;
#pragma unroll
        for (int c = 0; c < 3; ++c)
#pragma unroll
            for (int ii = 0; ii < 4; ++ii) {
                float4 v = make_float4(acc[c][ii][0], acc[c][ii][1],
                                       acc[c][ii][2], acc[c][ii][3]);
                *(float4*)&tb[c * GG + (i0 + ii) * 64 + j0] = v;
            }
    } else {
        float* ob = dst + (size_t)b * 3 * GG;
#pragma unroll
        for (int c = 0; c < 3; ++c)
#pragma unroll
            for (int ii = 0; ii < 4; ++ii)
#pragma unroll
                for (int jj = 0; jj < 4; ++jj)
                    atomicAdd(ob + c * GG + (i0 + ii) * 64 + j0 + jj,
                              acc[c][ii][jj]);
    }
}

// Stage 2 (partials path): reduce NCHUNK partials per cell + normalize.
// Grid: 8 b * 32 g-chunks = 256 blocks, 128 threads (1 cell each).
__global__ __launch_bounds__(128) void rbf_reduce(
    const float* __restrict__ ws, float* __restrict__ out)
{
    const int b = blockIdx.x >> 5;
    const int g = (blockIdx.x & 31) * 128 + threadIdx.x;

    float den = 0.f, sy = 0.f, st = 0.f;
#pragma unroll 4
    for (int k = 0; k < NCHUNK; ++k) {
        const float* p = ws + ((size_t)(b * NCHUNK + k) * 3) * GG + g;
        den += p[0];
        sy  += p[GG];
        st  += p[2 * GG];
    }
    float* ob = out + (size_t)b * 3 * GG;
    const float inv = 1.0f / (den + EPS);
    ob[g]          = den;
    ob[GG + g]     = sy * inv;
    ob[2 * GG + g] = st * inv;
}

// Stage 2 (atomic fallback): normalize in place.
__global__ __launch_bounds__(256) void rbf_norm(float* __restrict__ out)
{
    const int idx = blockIdx.x * 256 + threadIdx.x;   // over B*G
    const int b = idx >> 12;
    const int g = idx & (GG - 1);
    float* ob = out + (size_t)b * 3 * GG;
    const float inv = 1.0f / (ob[g] + EPS);
    ob[GG + g]     *= inv;
    ob[2 * GG + g] *= inv;
}

extern "C" void kernel_launch(void* const* d_in, const int* in_sizes, int n_in,
                              void* d_out, int out_size, void* d_ws, size_t ws_size,
                              hipStream_t stream) {
    const float* x_c  = (const float*)d_in[0];
    const float* y_c  = (const float*)d_in[1];
    const float* t_c  = (const float*)d_in[2];
    const int*   mask = (const int*)d_in[3];
    float* out = (float*)d_out;
    float* ws  = (float*)d_ws;

    const size_t need = (size_t)BB * NCHUNK * 3 * GG * sizeof(float); // 25.2 MB

    if (ws_size >= need) {
        rbf_stage1<1><<<BB * NCHUNK, TPB, 0, stream>>>(x_c, y_c, t_c, mask, ws);
        rbf_reduce<<<BB * 32, 128, 0, stream>>>(ws, out);
    } else {
        hipMemsetAsync(out, 0, (size_t)BB * 3 * GG * sizeof(float), stream);
        rbf_stage1<0><<<BB * NCHUNK, TPB, 0, stream>>>(x_c, y_c, t_c, mask, out);
        rbf_norm<<<(BB * GG) / 256, 256, 0, stream>>>(out);
    }
}

// Round 3
// 72.515 us; speedup vs baseline: 1.6466x; 1.2302x over previous
//
#include <hip/hip_runtime.h>

// Problem constants
#define BB 8
#define NN 4096
#define GG 4096            // 64x64 grid cells
#define KG 16              // k-groups (stage-1 blocks per batch)
#define CHUNKS 4           // point-chunks per block
#define CPTS 64            // points per chunk
#define TPB 256
#define PITCH 72           // f16 LDS row pitch (144 B: 16B-aligned, 2-way-max banks)

// -0.5/sigma^2 * log2(e), sigma=0.1
#define C2 (-72.13475204444817f)
#define STEP (2.0f / 63.0f)
#define EPS 1e-5f

typedef _Float16 f16x8 __attribute__((ext_vector_type(8)));
typedef float f32x4 __attribute__((ext_vector_type(4)));

__device__ __forceinline__ float gcoord(int j) { return fmaf((float)j, STEP, -1.0f); }

// Stage 1: per (b, kgroup) compute C(192x64) = At(192x64pts) @ Wx(64pts x 64)
// accumulated over CHUNKS chunks of 64 points, via f16 MFMA 16x16x32.
// Rows of C: [density | wy*y | wy*t] x 64 y-rows. PARTIAL=1: write tile to ws;
// PARTIAL=0: atomicAdd into out.
template <int PARTIAL>
__global__ __launch_bounds__(TPB) void rbf_stage1(
    const float* __restrict__ x_c,   // (B,N,2)
    const float* __restrict__ y_c,   // (B,N)
    const float* __restrict__ t_c,   // (B,N)
    const int*  __restrict__ mask,   // (B,N) int32, nonzero = drop
    float* __restrict__ dst)
{
    __shared__ _Float16 At[192][PITCH];   // 27.6 KB: rows r=c*64+i, k=point
    __shared__ _Float16 wxT[64][PITCH];   // 9.2 KB: rows = grid col j, k=point
    __shared__ float4 pts[CPTS];          // {px, py(or 1e9 if masked), y, t}

    const int kg   = blockIdx.x & (KG - 1);
    const int b    = blockIdx.x >> 4;
    const int tid  = threadIdx.x;
    const int wv   = tid >> 6;       // wave 0..3
    const int lane = tid & 63;
    const int quad = lane >> 4;
    const int lr   = lane & 15;
    const int jcol = tid & 63;       // serves as both grid col (wx) and y-row (At)
    const int grp  = tid >> 6;       // 16-point group
    const float gj = gcoord(jcol);

    f32x4 acc[3][4];
#pragma unroll
    for (int mt = 0; mt < 3; ++mt)
#pragma unroll
        for (int nt = 0; nt < 4; ++nt) acc[mt][nt] = (f32x4){0.f, 0.f, 0.f, 0.f};

    for (int ch = 0; ch < CHUNKS; ++ch) {
        // ---- stage this chunk's 64 points ----
        if (tid < CPTS) {
            const int n = b * NN + (kg * CHUNKS + ch) * CPTS + tid;
            const float2 xv = ((const float2*)x_c)[n];
            const float py = mask[n] ? 1.0e9f : xv.y;  // masked -> wy underflows to 0
            pts[tid] = make_float4(xv.x, py, y_c[n], t_c[n]);
        }
        __syncthreads();

        // ---- Phase A: separable f16 weights, transposed (k-contiguous) ----
#pragma unroll
        for (int h = 0; h < 2; ++h) {
            f16x8 vx, ve, vy, vt;
#pragma unroll
            for (int e = 0; e < 8; ++e) {
                const float4 P = pts[grp * 16 + h * 8 + e];   // wave-uniform bcast
                const float dx = P.x - gj;
                vx[e] = (_Float16)exp2f(C2 * dx * dx);
                const float dy = P.y - gj;
                const float ex = exp2f(C2 * dy * dy);
                ve[e] = (_Float16)ex;
                vy[e] = (_Float16)(ex * P.z);
                vt[e] = (_Float16)(ex * P.w);
            }
            const int o = grp * 16 + h * 8;
            *(f16x8*)&wxT[jcol][o]      = vx;
            *(f16x8*)&At[jcol][o]       = ve;
            *(f16x8*)&At[64 + jcol][o]  = vy;
            *(f16x8*)&At[128 + jcol][o] = vt;
        }
        __syncthreads();

        // ---- Phase B: 24 MFMAs. Wave owns rows [wv*48, wv*48+48) x all 64 cols
        // A-frag: A[m=lr][k=quad*8+j]; B-frag: B[k=quad*8+j][n=lr]; both 1x b128.
#pragma unroll
        for (int ks = 0; ks < 2; ++ks) {
            const int kb = ks * 32 + quad * 8;
            f16x8 a[3], bf[4];
#pragma unroll
            for (int mt = 0; mt < 3; ++mt)
                a[mt] = *(const f16x8*)&At[wv * 48 + mt * 16 + lr][kb];
#pragma unroll
            for (int nt = 0; nt < 4; ++nt)
                bf[nt] = *(const f16x8*)&wxT[nt * 16 + lr][kb];
#pragma unroll
            for (int mt = 0; mt < 3; ++mt)
#pragma unroll
                for (int nt = 0; nt < 4; ++nt)
                    acc[mt][nt] = __builtin_amdgcn_mfma_f32_16x16x32_f16(
                        a[mt], bf[nt], acc[mt][nt], 0, 0, 0);
        }
        // no barrier needed here: next iter's pts-store doesn't touch At/wxT,
        // and the post-pts sync orders Phase B(ch) before Phase A(ch+1).
    }

    // ---- epilogue: C/D layout col=lr, row=quad*4+reg ----
    if (PARTIAL) {
        float* tb = dst + ((size_t)(b * KG + kg) * 192) * 64;
#pragma unroll
        for (int mt = 0; mt < 3; ++mt)
#pragma unroll
            for (int nt = 0; nt < 4; ++nt)
#pragma unroll
                for (int r = 0; r < 4; ++r) {
                    const int row = wv * 48 + mt * 16 + quad * 4 + r;
                    tb[row * 64 + nt * 16 + lr] = acc[mt][nt][r];
                }
    } else {
        float* ob = dst + (size_t)b * 3 * GG;
#pragma unroll
        for (int mt = 0; mt < 3; ++mt)
#pragma unroll
            for (int nt = 0; nt < 4; ++nt)
#pragma unroll
                for (int r = 0; r < 4; ++r) {
                    const int row = wv * 48 + mt * 16 + quad * 4 + r;
                    atomicAdd(ob + row * 64 + nt * 16 + lr, acc[mt][nt][r]);
                }
    }
}

// Stage 2: sum KG partials per cell + normalize. 128 blocks x 256 threads.
__global__ __launch_bounds__(256) void rbf_reduce(
    const float* __restrict__ ws, float* __restrict__ out)
{
    const int idx = blockIdx.x * 256 + threadIdx.x;   // over B*G
    const int b = idx >> 12;
    const int g = idx & (GG - 1);
    float den = 0.f, sy = 0.f, st = 0.f;
    const float* p = ws + ((size_t)b * KG * 3) * GG + g;
#pragma unroll 4
    for (int k = 0; k < KG; ++k) {
        den += p[0];
        sy  += p[GG];
        st  += p[2 * GG];
        p += 3 * GG;
    }
    float* ob = out + (size_t)b * 3 * GG;
    const float inv = 1.0f / (den + EPS);
    ob[g]          = den;
    ob[GG + g]     = sy * inv;
    ob[2 * GG + g] = st * inv;
}

// Fallback normalize (atomic path).
__global__ __launch_bounds__(256) void rbf_norm(float* __restrict__ out)
{
    const int idx = blockIdx.x * 256 + threadIdx.x;
    const int b = idx >> 12;
    const int g = idx & (GG - 1);
    float* ob = out + (size_t)b * 3 * GG;
    const float inv = 1.0f / (ob[g] + EPS);
    ob[GG + g]     *= inv;
    ob[2 * GG + g] *= inv;
}

extern "C" void kernel_launch(void* const* d_in, const int* in_sizes, int n_in,
                              void* d_out, int out_size, void* d_ws, size_t ws_size,
                              hipStream_t stream) {
    const float* x_c  = (const float*)d_in[0];
    const float* y_c  = (const float*)d_in[1];
    const float* t_c  = (const float*)d_in[2];
    const int*   mask = (const int*)d_in[3];
    float* out = (float*)d_out;
    float* ws  = (float*)d_ws;

    const size_t need = (size_t)BB * KG * 192 * 64 * sizeof(float); // 6.3 MB

    if (ws_size >= need) {
        rbf_stage1<1><<<BB * KG, TPB, 0, stream>>>(x_c, y_c, t_c, mask, ws);
        rbf_reduce<<<(BB * GG) / 256, 256, 0, stream>>>(ws, out);
    } else {
        hipMemsetAsync(out, 0, (size_t)BB * 3 * GG * sizeof(float), stream);
        rbf_stage1<0><<<BB * KG, TPB, 0, stream>>>(x_c, y_c, t_c, mask, out);
        rbf_norm<<<(BB * GG) / 256, 256, 0, stream>>>(out);
    }
}

// Round 4
// 72.061 us; speedup vs baseline: 1.6569x; 1.0063x over previous
//
#include <hip/hip_runtime.h>

// Problem constants
#define BB 8
#define NN 4096
#define GG 4096            // 64x64 grid cells
#define KG 32              // k-groups (stage-1 blocks per batch) -> 256 blocks
#define CHUNKS 2           // point-chunks per block
#define CPTS 64            // points per chunk
#define TPB 256
#define PITCH 72           // f16 LDS row pitch (144 B: 16B-aligned)

// -0.5/sigma^2 * log2(e), sigma=0.1
#define C2 (-72.13475204444817f)
#define STEP (2.0f / 63.0f)
#define EPS 1e-5f

typedef _Float16 f16x8 __attribute__((ext_vector_type(8)));
typedef float f32x4 __attribute__((ext_vector_type(4)));

__device__ __forceinline__ float gcoord(int j) { return fmaf((float)j, STEP, -1.0f); }

// Stage 1: per (b, kgroup) compute C(192x64) = At(192x128pts) @ Wx(128pts x 64)
// over CHUNKS chunks of 64 points, via f16 MFMA 16x16x32.
// Rows of C: [density | wy*y | wy*t] x 64 y-rows. PARTIAL=1: write tile to ws;
// PARTIAL=0: atomicAdd into out.
template <int PARTIAL>
__global__ __launch_bounds__(TPB) void rbf_stage1(
    const float* __restrict__ x_c,   // (B,N,2)
    const float* __restrict__ y_c,   // (B,N)
    const float* __restrict__ t_c,   // (B,N)
    const int*  __restrict__ mask,   // (B,N) int32, nonzero = drop
    float* __restrict__ dst)
{
    __shared__ _Float16 At[192][PITCH];     // 27.6 KB: rows r=c*64+i, k=point
    __shared__ _Float16 wxT[64][PITCH];     // 9.2 KB: rows = grid col j, k=point
    __shared__ float4 pts[CHUNKS][CPTS];    // {px, py(or 1e9 if masked), y, t}

    const int kg   = blockIdx.x & (KG - 1);
    const int b    = blockIdx.x / KG;
    const int tid  = threadIdx.x;
    const int wv   = tid >> 6;       // wave 0..3
    const int lane = tid & 63;
    const int quad = lane >> 4;
    const int lr   = lane & 15;
    const int jcol = tid & 63;       // grid col (wx) / y-row (At)
    const int grp  = tid >> 6;       // 16-point group
    const float gj = gcoord(jcol);

    // ---- stage BOTH chunks' points up front (one global-latency window) ----
    if (tid < CHUNKS * CPTS) {
        const int c = tid >> 6, p = tid & 63;
        const int n = b * NN + (kg * CHUNKS + c) * CPTS + p;
        const float2 xv = ((const float2*)x_c)[n];
        const float py = mask[n] ? 1.0e9f : xv.y;  // masked -> wy underflows to 0
        pts[c][p] = make_float4(xv.x, py, y_c[n], t_c[n]);
    }

    f32x4 acc[3][4];
#pragma unroll
    for (int mt = 0; mt < 3; ++mt)
#pragma unroll
        for (int nt = 0; nt < 4; ++nt) acc[mt][nt] = (f32x4){0.f, 0.f, 0.f, 0.f};

    __syncthreads();

    for (int ch = 0; ch < CHUNKS; ++ch) {
        // ---- Phase A: separable f16 weights, transposed (k-contiguous) ----
#pragma unroll
        for (int h = 0; h < 2; ++h) {
            f16x8 vx, ve, vy, vt;
#pragma unroll
            for (int e = 0; e < 8; ++e) {
                const float4 P = pts[ch][grp * 16 + h * 8 + e]; // wave-uniform bcast
                const float dx = P.x - gj;
                vx[e] = (_Float16)exp2f(C2 * dx * dx);
                const float dy = P.y - gj;
                const float ex = exp2f(C2 * dy * dy);
                ve[e] = (_Float16)ex;
                vy[e] = (_Float16)(ex * P.z);
                vt[e] = (_Float16)(ex * P.w);
            }
            const int o = grp * 16 + h * 8;
            *(f16x8*)&wxT[jcol][o]      = vx;
            *(f16x8*)&At[jcol][o]       = ve;
            *(f16x8*)&At[64 + jcol][o]  = vy;
            *(f16x8*)&At[128 + jcol][o] = vt;
        }
        __syncthreads();

        // ---- Phase B: 24 MFMAs. Wave owns rows [wv*48, wv*48+48) x all 64 cols
        // A-frag: A[m=lr][k=quad*8+j]; B-frag: B[k=quad*8+j][n=lr]; both 1x b128.
#pragma unroll
        for (int ks = 0; ks < 2; ++ks) {
            const int kb = ks * 32 + quad * 8;
            f16x8 a[3], bf[4];
#pragma unroll
            for (int mt = 0; mt < 3; ++mt)
                a[mt] = *(const f16x8*)&At[wv * 48 + mt * 16 + lr][kb];
#pragma unroll
            for (int nt = 0; nt < 4; ++nt)
                bf[nt] = *(const f16x8*)&wxT[nt * 16 + lr][kb];
#pragma unroll
            for (int mt = 0; mt < 3; ++mt)
#pragma unroll
                for (int nt = 0; nt < 4; ++nt)
                    acc[mt][nt] = __builtin_amdgcn_mfma_f32_16x16x32_f16(
                        a[mt], bf[nt], acc[mt][nt], 0, 0, 0);
        }
        if (ch + 1 < CHUNKS) __syncthreads();   // B(ch) before A(ch+1) rewrites LDS
    }

    // ---- epilogue: C/D layout col=lr, row=quad*4+reg ----
    if (PARTIAL) {
        float* tb = dst + ((size_t)(b * KG + kg) * 192) * 64;
#pragma unroll
        for (int mt = 0; mt < 3; ++mt)
#pragma unroll
            for (int nt = 0; nt < 4; ++nt)
#pragma unroll
                for (int r = 0; r < 4; ++r) {
                    const int row = wv * 48 + mt * 16 + quad * 4 + r;
                    tb[row * 64 + nt * 16 + lr] = acc[mt][nt][r];
                }
    } else {
        float* ob = dst + (size_t)b * 3 * GG;
#pragma unroll
        for (int mt = 0; mt < 3; ++mt)
#pragma unroll
            for (int nt = 0; nt < 4; ++nt)
#pragma unroll
                for (int r = 0; r < 4; ++r) {
                    const int row = wv * 48 + mt * 16 + quad * 4 + r;
                    atomicAdd(ob + row * 64 + nt * 16 + lr, acc[mt][nt][r]);
                }
    }
}

// Stage 2: sum KG partials per cell + normalize. 128 blocks x 256 threads.
__global__ __launch_bounds__(256) void rbf_reduce(
    const float* __restrict__ ws, float* __restrict__ out)
{
    const int idx = blockIdx.x * 256 + threadIdx.x;   // over B*G
    const int b = idx >> 12;
    const int g = idx & (GG - 1);
    float den = 0.f, sy = 0.f, st = 0.f;
    const float* p = ws + ((size_t)b * KG * 3) * GG + g;
#pragma unroll 4
    for (int k = 0; k < KG; ++k) {
        den += p[0];
        sy  += p[GG];
        st  += p[2 * GG];
        p += 3 * GG;
    }
    float* ob = out + (size_t)b * 3 * GG;
    const float inv = 1.0f / (den + EPS);
    ob[g]          = den;
    ob[GG + g]     = sy * inv;
    ob[2 * GG + g] = st * inv;
}

// Fallback normalize (atomic path).
__global__ __launch_bounds__(256) void rbf_norm(float* __restrict__ out)
{
    const int idx = blockIdx.x * 256 + threadIdx.x;
    const int b = idx >> 12;
    const int g = idx & (GG - 1);
    float* ob = out + (size_t)b * 3 * GG;
    const float inv = 1.0f / (ob[g] + EPS);
    ob[GG + g]     *= inv;
    ob[2 * GG + g] *= inv;
}

extern "C" void kernel_launch(void* const* d_in, const int* in_sizes, int n_in,
                              void* d_out, int out_size, void* d_ws, size_t ws_size,
                              hipStream_t stream) {
    const float* x_c  = (const float*)d_in[0];
    const float* y_c  = (const float*)d_in[1];
    const float* t_c  = (const float*)d_in[2];
    const int*   mask = (const int*)d_in[3];
    float* out = (float*)d_out;
    float* ws  = (float*)d_ws;

    const size_t need = (size_t)BB * KG * 192 * 64 * sizeof(float); // 12.6 MB

    if (ws_size >= need) {
        rbf_stage1<1><<<BB * KG, TPB, 0, stream>>>(x_c, y_c, t_c, mask, ws);
        rbf_reduce<<<(BB * GG) / 256, 256, 0, stream>>>(ws, out);
    } else {
        hipMemsetAsync(out, 0, (size_t)BB * 3 * GG * sizeof(float), stream);
        rbf_stage1<0><<<BB * KG, TPB, 0, stream>>>(x_c, y_c, t_c, mask, out);
        rbf_norm<<<(BB * GG) / 256, 256, 0, stream>>>(out);
    }
}